// Round 6
// baseline (716.476 us; speedup 1.0000x reference)
//
#include <hip/hip_runtime.h>
#include <cstdint>
#include <cstddef>

// ---------- types / helpers ----------
typedef __bf16 bf16x8 __attribute__((ext_vector_type(8)));
typedef float  floatx4 __attribute__((ext_vector_type(4)));
typedef unsigned short ushort8 __attribute__((ext_vector_type(8)));
typedef unsigned short ushort4v __attribute__((ext_vector_type(4)));

__device__ __forceinline__ float bf2f(unsigned short u) {
    union { unsigned int u32; float f; } x; x.u32 = ((unsigned int)u) << 16; return x.f;
}
__device__ __forceinline__ float bflo(unsigned int u) {
    union { unsigned int u32; float f; } x; x.u32 = u << 16; return x.f;
}
__device__ __forceinline__ float bfhi(unsigned int u) {
    union { unsigned int u32; float f; } x; x.u32 = u & 0xffff0000u; return x.f;
}
__device__ __forceinline__ unsigned short f2bf(float f) {
    union { float f; unsigned int u; } x; x.f = f;
    unsigned int u = x.u;
    unsigned int r = (u + 0x7fffu + ((u >> 16) & 1u)) >> 16;   // RNE
    return (unsigned short)r;
}

#define GLOBAL_U32 const __attribute__((address_space(1))) unsigned int*
#define LDS_U32 __attribute__((address_space(3))) unsigned int*
__device__ __forceinline__ void async_cp16(const void* g, void* l) {
    __builtin_amdgcn_global_load_lds((GLOBAL_U32)g, (LDS_U32)l, 16, 0, 0);
}

// ---------- conv1 (oh-split x2): x[256,1,28,28]*w[256,1,9,9] -> h1t bf16 [b][20][20][256] ----------
__global__ __launch_bounds__(256) void conv1_k(const float* __restrict__ x,
                                               const float* __restrict__ w,
                                               const float* __restrict__ bias,
                                               unsigned short* __restrict__ h1t) {
    const int bb = blockIdx.x, t = threadIdx.x;
    const int b = bb >> 1, h = bb & 1;
    const int oh0 = h * 10;
    __shared__ float xs[18 * 28];
    for (int idx = t; idx < 504; idx += 256) xs[idx] = x[b * 784 + oh0 * 28 + idx];
    __syncthreads();
    const float* wr = w + t * 81;   // thread t = output channel t
    const float bv = bias[t];
    for (int ohl = 0; ohl < 10; ++ohl) {
        float acc[20];
#pragma unroll
        for (int ow = 0; ow < 20; ++ow) acc[ow] = bv;
#pragma unroll
        for (int kh = 0; kh < 9; ++kh) {
            float xr[28];
            const float* xrow = &xs[(ohl + kh) * 28];
#pragma unroll
            for (int q = 0; q < 7; ++q) *(float4*)&xr[q * 4] = *(const float4*)&xrow[q * 4];
#pragma unroll
            for (int kw = 0; kw < 9; ++kw) {
                const float wv = wr[kh * 9 + kw];
#pragma unroll
                for (int ow = 0; ow < 20; ++ow) acc[ow] = fmaf(xr[ow + kw], wv, acc[ow]);
            }
        }
        unsigned short* orow = h1t + (size_t)((b * 20 + oh0 + ohl) * 20) * 256 + t;
#pragma unroll
        for (int ow = 0; ow < 20; ++ow) orow[ow * 256] = f2bf(acc[ow]);
    }
}

// ---------- w2 transform: OIHW fp32 [oc][ic][81] -> bf16 [oc][tap*256+ic] ----------
__global__ __launch_bounds__(256) void w2t_k(const float* __restrict__ w2,
                                             unsigned short* __restrict__ w2t) {
    const int oc = blockIdx.x >> 1, half = blockIdx.x & 1, t = threadIdx.x;
    __shared__ float ws[10368];                       // 128 ic * 81 taps
    const float* src = w2 + (size_t)oc * 20736 + half * 128 * 81;
    for (int idx = t; idx < 10368; idx += 256) ws[idx] = src[idx];
    __syncthreads();
    unsigned short* dst = w2t + (size_t)oc * 20736 + half * 128;
    for (int idx = t; idx < 10368; idx += 256) {
        const int tap = idx >> 7, icl = idx & 127;
        dst[tap * 256 + icl] = f2bf(ws[icl * 81 + tap]);
    }
}

// ---------- conv2 as implicit GEMM, bf16 MFMA, split-K x8, BK=64, swizzled LDS ----------
__device__ __forceinline__ int c2_rowbase(int m) {
    const int b = m / 36, sp = m % 36;
    const int oh = sp / 6, ow = sp % 6;
    return (b * 400 + oh * 40 + ow * 2) * 256;        // element offset into h1t
}

__global__ __launch_bounds__(256) void conv2_k(const unsigned short* __restrict__ h1t,
                                               const unsigned short* __restrict__ w2t,
                                               unsigned short* __restrict__ part) {
    const int t = threadIdx.x;
    // XCD-locality swizzle: bx-siblings of one (by,z) are 8 ids apart (same
    // XCD under round-robin), z decorrelated from XCD. Pure-perf bijection.
    const int id = blockIdx.x;                        // 0..1151
    const int bx = (id >> 3) & 1;
    const int by = id >> 4;                           // 0..71
    const int z  = ((id & 7) + by) & 7;               // 0..7
    __shared__ unsigned short At[128 * 64];           // m rows, 64 bf16 (K-pair)
    __shared__ unsigned short Bt[128 * 64];           // oc rows

    const int oc0 = bx * 128;

    // staging: each thread stages 4 A-units and 4 B-units (16B each).
    // LDS slot a = t + 256*k; row = a>>3, phys slot s = a&7 holds logical
    // unit u = s ^ (row&7)  (bank-conflict-free b128 reads).
    int aRB[4], aCU[4], bBase[4];
#pragma unroll
    for (int k = 0; k < 4; ++k) {
        const int a = t + 256 * k;
        const int r = a >> 3, s = a & 7;
        const int u = s ^ (r & 7);
        aRB[k] = c2_rowbase(by * 128 + r) + (u & 3) * 8;
        aCU[k] = u >> 2;                              // which chunk of the pair
        bBase[k] = (oc0 + r) * 20736 + (u >> 2) * 32 + (u & 3) * 8;
    }

    const int lane = t & 63, l15 = lane & 15, quad = lane >> 4;
    const int wave = t >> 6;
    const int wOC = (wave & 1) * 64, wM = (wave >> 1) * 64;

    // fragment LDS offsets (ushort units): row stride 64, unit u = h*4+quad
    int aO[2][4], bO[2][4];
#pragma unroll
    for (int i = 0; i < 4; ++i) {
        const int R = wOC + i * 16 + l15;             // oc row (A-operand from Bt)
#pragma unroll
        for (int h = 0; h < 2; ++h)
            aO[h][i] = R * 64 + (((h * 4 + quad) ^ (R & 7)) << 3);
    }
#pragma unroll
    for (int j = 0; j < 4; ++j) {
        const int R = wM + j * 16 + l15;              // m row (B-operand from At)
#pragma unroll
        for (int h = 0; h < 2; ++h)
            bO[h][j] = R * 64 + (((h * 4 + quad) ^ (R & 7)) << 3);
    }

    floatx4 acc[4][4];
#pragma unroll
    for (int i = 0; i < 4; ++i)
#pragma unroll
        for (int j = 0; j < 4; ++j) acc[i][j] = (floatx4){0.f, 0.f, 0.f, 0.f};

    // K = 648 chunks = 324 pairs; z covers pairs [p0,p1)
    const int p0 = (324 * z) >> 3, p1 = (324 * (z + 1)) >> 3;
    for (int p = p0; p < p1; ++p) {
        const int tap = p >> 2;                       // both chunks of a pair share tap
        const int kh = tap / 9, kw = tap - 9 * kh;
        const int aoffB = (kh * 20 + kw) * 256;
        const int ce7 = (2 * p) & 7;
        __syncthreads();
#pragma unroll
        for (int k = 0; k < 4; ++k)
            async_cp16(h1t + aRB[k] + aoffB + (ce7 + aCU[k]) * 32, At + (t + 256 * k) * 8);
#pragma unroll
        for (int k = 0; k < 4; ++k)
            async_cp16(w2t + bBase[k] + p * 64, Bt + (t + 256 * k) * 8);
        __syncthreads();
#pragma unroll
        for (int h = 0; h < 2; ++h) {
            bf16x8 aF[4], bF[4];
#pragma unroll
            for (int i = 0; i < 4; ++i) aF[i] = *(const bf16x8*)(Bt + aO[h][i]);
#pragma unroll
            for (int j = 0; j < 4; ++j) bF[j] = *(const bf16x8*)(At + bO[h][j]);
#pragma unroll
            for (int i = 0; i < 4; ++i)
#pragma unroll
                for (int j = 0; j < 4; ++j)
                    acc[i][j] = __builtin_amdgcn_mfma_f32_16x16x32_bf16(aF[i], bF[j], acc[i][j], 0, 0, 0);
        }
    }

    // epilogue: D[reg->oc][lane->m]; pack 4 bf16 along n, store to PART[z][m][n]
    unsigned short* pz = part + (size_t)z * 2359296;
#pragma unroll
    for (int i = 0; i < 4; ++i) {
        const int n0 = oc0 + wOC + i * 16 + quad * 4;
#pragma unroll
        for (int j = 0; j < 4; ++j) {
            const int m = by * 128 + wM + j * 16 + l15;
            ushort4v pk;
#pragma unroll
            for (int r = 0; r < 4; ++r) pk[r] = f2bf(acc[i][j][r]);
            *(ushort4v*)(pz + (size_t)m * 256 + n0) = pk;
        }
    }
}

// ---------- reduce split-K(bf16 x8) + bias + squash(axis=w) -> u[b][1152][8] (half-split x2) ----------
__global__ __launch_bounds__(256) void squash_u_k(const unsigned short* __restrict__ part,
                                                  const float* __restrict__ bias,
                                                  float* __restrict__ u) {
    const int bb = blockIdx.x, t = threadIdx.x;
    const int b = bb >> 1, h = bb & 1;
    __shared__ float hs[4608];
    const size_t base = (size_t)b * 9216 + h * 4608;
    for (int q = t; q < 2304; q += 256) {
        const int idx = q * 2;
        float v0 = bias[idx & 255], v1 = bias[(idx + 1) & 255];
#pragma unroll
        for (int z = 0; z < 8; ++z) {
            const unsigned int uu = *(const unsigned int*)(part + (size_t)z * 2359296 + base + idx);
            v0 += bflo(uu);
            v1 += bfhi(uu);
        }
        hs[idx] = v0; hs[idx + 1] = v1;
    }
    __syncthreads();
    for (int gq = t; gq < 768; gq += 256) {           // groups (c, oh-local), squash over ow(6)
        const int c = gq / 3, ohl = gq % 3;
        const int oh = h * 3 + ohl;
        float s[6], sq = 0.f;
#pragma unroll
        for (int ow = 0; ow < 6; ++ow) { s[ow] = hs[(ohl * 6 + ow) * 256 + c]; sq = fmaf(s[ow], s[ow], sq); }
        const float norm = sqrtf(sq);
        const float f = (sq / (1.0f + sq)) / (norm + 1e-7f);
        float* up = u + (size_t)b * 9216 + c * 36 + oh * 6;
#pragma unroll
        for (int ow = 0; ow < 6; ++ow) up[ow] = s[ow] * f;
    }
}

// ---------- Wr2[od][k] = 0.1 * Wc[o][i][d][e]  (od=o*16+d, k=i*8+e) ----------
__global__ __launch_bounds__(256) void wr_k(const float* __restrict__ Wc,
                                            float* __restrict__ Wr2) {
    const int od = blockIdx.x, t = threadIdx.x;       // 160 blocks
    const int o = od >> 4, d = od & 15;
    const float* src = Wc + (size_t)o * 147456 + d * 8;
    float* dst = Wr2 + (size_t)od * 9216;
    for (int idx = t; idx < 9216; idx += 256) {
        const int i = idx >> 3, e = idx & 7;
        dst[idx] = 0.1f * src[(size_t)i * 128 + e];
    }
}

// ---------- S0[b][od] = sum_k u[b][k] * Wr2[od][k]  (replaces routing iter 0) ----------
__global__ __launch_bounds__(160) void s0_k(const float* __restrict__ u,
                                            const float* __restrict__ Wr2,
                                            float* __restrict__ S0) {
    const int b = blockIdx.x, kq = blockIdx.y, t = threadIdx.x;   // t = od
    __shared__ __align__(16) float us[2304];
    const float* ub = u + (size_t)b * 9216 + kq * 2304;
    for (int idx = t; idx < 2304; idx += 160) us[idx] = ub[idx];
    __syncthreads();
    const float* wp = Wr2 + (size_t)t * 9216 + kq * 2304;
    float acc = 0.f;
#pragma unroll 4
    for (int k4 = 0; k4 < 576; ++k4) {
        const float4 wv = *(const float4*)(wp + k4 * 4);
        const float4 uv = *(const float4*)(&us[k4 * 4]);
        acc = fmaf(wv.x, uv.x, acc);
        acc = fmaf(wv.y, uv.y, acc);
        acc = fmaf(wv.z, uv.z, acc);
        acc = fmaf(wv.w, uv.w, acc);
    }
    atomicAdd(&S0[b * 160 + t], acc);
}

// ---------- u_hat[b][i][o*16+d] bf16 = sum_e W[o,i,d,e]*u[b,i,e] ----------
__global__ __launch_bounds__(256) void uhat_k(const float* __restrict__ Wc,
                                              const float* __restrict__ u,
                                              unsigned short* __restrict__ uhat) {
    const int i = blockIdx.x, t = threadIdx.x;       // t = b
    __shared__ float Wl[1280];                       // [o][d*8+e]
    __shared__ unsigned short Ul[128 * 168];         // padded transpose buffer (43 KB)
    for (int idx = t; idx < 1280; idx += 256) {
        const int o = idx >> 7, r = idx & 127;
        Wl[idx] = Wc[((size_t)o * 1152 + i) * 128 + r];
    }
    float ur[8];
    *(float4*)&ur[0] = *(const float4*)(u + (size_t)t * 9216 + i * 8);
    *(float4*)&ur[4] = *(const float4*)(u + (size_t)t * 9216 + i * 8 + 4);
    __syncthreads();
    unsigned short val[160];
#pragma unroll 1
    for (int o = 0; o < 10; ++o) {
#pragma unroll
        for (int d = 0; d < 16; ++d) {
            const float* wp = &Wl[o * 128 + d * 8];
            float a = 0.f;
#pragma unroll
            for (int e = 0; e < 8; ++e) a = fmaf(wp[e], ur[e], a);
            val[o * 16 + d] = f2bf(a);
        }
    }
#pragma unroll 1
    for (int h = 0; h < 2; ++h) {
        __syncthreads();
        if ((t >> 7) == h) {
            unsigned short* row = &Ul[(t & 127) * 168];
#pragma unroll
            for (int q = 0; q < 20; ++q) *(ushort8*)(row + q * 8) = *(const ushort8*)(val + q * 8);
        }
        __syncthreads();
        for (int idx = t; idx < 2560; idx += 256) {
            const int r = idx / 20, q = idx % 20;
            const int b = h * 128 + r;
            *(ushort8*)(uhat + ((size_t)b * 1152 + i) * 160 + q * 8) =
                *(const ushort8*)(&Ul[r * 168 + q * 8]);
        }
    }
}

// ---------- fused routing iteration: squash(S_in) + logit update + softmax + weighted sum ----------
template <int ITER>
__global__ __launch_bounds__(256) void route_iter_k(const unsigned short* __restrict__ uhat,
                                                    const float* __restrict__ S_in,
                                                    float* __restrict__ BL,
                                                    float* __restrict__ S_out) {
    const int b = blockIdx.x, i0 = blockIdx.y * 128, t = threadIdx.x;
    __shared__ __align__(16) unsigned short Ul[128 * 160];   // 40960 B
    __shared__ float Vl[160];
    __shared__ float cT[10 * 132];
    __shared__ float dots[128 * 10];

    const char* gsrc = (const char*)(uhat + ((size_t)b * 1152 + i0) * 160);
#pragma unroll
    for (int rep = 0; rep < 10; ++rep)
        async_cp16(gsrc + rep * 4096 + t * 16, (char*)Ul + rep * 4096 + t * 16);

    // phase 0: squash S_in -> Vl (redundant per block; 160 floats)
    if (t < 160) {
        const float x = S_in[b * 160 + t];
        float sq = x * x;
        sq += __shfl_xor(sq, 1, 16);
        sq += __shfl_xor(sq, 2, 16);
        sq += __shfl_xor(sq, 4, 16);
        sq += __shfl_xor(sq, 8, 16);
        const float norm = sqrtf(sq);
        const float f = (sq / (1.f + sq)) / (norm + 1e-7f);
        Vl[t] = x * f;
    }
    __syncthreads();                                  // drains async + Vl visible

    // p1a mapping: o = t%10 fixed per thread, strip s = t/10 (250 active)
    const int o = t % 10, s = t / 10;
    float vr[16];
    if (t < 250) {
#pragma unroll
        for (int q = 0; q < 4; ++q)
            *(float4*)&vr[q * 4] = *(const float4*)(&Vl[o * 16 + q * 4]);
    }

    // p1a: dots[i][o] = sum_d u_hat[i,o,d] * v[o,d]
    if (t < 250) {
#pragma unroll
        for (int rep = 0; rep < 6; ++rep) {
            const int i = s + 25 * rep;
            if (i < 128) {
                const ushort8 ua = *(const ushort8*)(Ul + i * 160 + o * 16);
                const ushort8 ub = *(const ushort8*)(Ul + i * 160 + o * 16 + 8);
                float dot = 0.f;
#pragma unroll
                for (int d = 0; d < 8; ++d) dot = fmaf(bf2f(ua[d]), vr[d], dot);
#pragma unroll
                for (int d = 0; d < 8; ++d) dot = fmaf(bf2f(ub[d]), vr[8 + d], dot);
                dots[i * 10 + o] = dot;
            }
        }
    }
    __syncthreads();

    // p1b: per-i logits + softmax -> cT[o][i]
    if (t < 128) {
        float bl[10];
#pragma unroll
        for (int oo = 0; oo < 10; ++oo) bl[oo] = dots[t * 10 + oo];
        if (ITER == 2) {
#pragma unroll
            for (int oo = 0; oo < 10; ++oo) bl[oo] += BL[(size_t)b * 11520 + oo * 1152 + i0 + t];
        } else {
#pragma unroll
            for (int oo = 0; oo < 10; ++oo) BL[(size_t)b * 11520 + oo * 1152 + i0 + t] = bl[oo];
        }
        float mx = bl[0];
#pragma unroll
        for (int oo = 1; oo < 10; ++oo) mx = fmaxf(mx, bl[oo]);
        float ex[10], sum = 0.f;
#pragma unroll
        for (int oo = 0; oo < 10; ++oo) { ex[oo] = expf(bl[oo] - mx); sum += ex[oo]; }
        const float inv = 1.f / sum;
#pragma unroll
        for (int oo = 0; oo < 10; ++oo) cT[oo * 132 + t] = ex[oo] * inv;
    }
    __syncthreads();

    // p2: S_out[b][160] += sum_i c[i][o] * u_hat[i][od]  (two 64-i halves)
    const int th = t & 127, hi = t >> 7;
    if (th < 80) {
        const int o8 = th >> 3;
        const unsigned int* base = (const unsigned int*)Ul + (size_t)hi * 64 * 80 + th;
        const float* cb = &cT[o8 * 132 + hi * 64];
        float ax = 0.f, ay = 0.f;
#pragma unroll 4
        for (int ii = 0; ii < 64; ++ii) {
            const float c = cb[ii];
            const unsigned int uu = base[ii * 80];
            ax = fmaf(c, bflo(uu), ax);
            ay = fmaf(c, bfhi(uu), ay);
        }
        atomicAdd(&S_out[b * 160 + 2 * th], ax);
        atomicAdd(&S_out[b * 160 + 2 * th + 1], ay);
    }
}

// ---------- final: squash S2 -> lengths, argmax + fused decoder layer 1 ----------
__global__ __launch_bounds__(512) void final_k(const float* __restrict__ S,
                                               const float* __restrict__ w1,
                                               const float* __restrict__ b1,
                                               float* __restrict__ out_len,
                                               float* __restrict__ h1d) {
    const int b = blockIdx.x, t = threadIdx.x;
    __shared__ float v_s[160];
    __shared__ float len_s[10];
    __shared__ int sel_s;
    if (t < 160) {
        const float x = S[b * 160 + t];
        float sq = x * x;
        sq += __shfl_xor(sq, 1, 16);
        sq += __shfl_xor(sq, 2, 16);
        sq += __shfl_xor(sq, 4, 16);
        sq += __shfl_xor(sq, 8, 16);
        const float norm = sqrtf(sq);
        const float f = (sq / (1.f + sq)) / (norm + 1e-7f);
        v_s[t] = x * f;
        if ((t & 15) == 0) {
            const float len = f * norm;
            len_s[t >> 4] = len;
            out_len[b * 10 + (t >> 4)] = len;
        }
    }
    __syncthreads();
    if (t == 0) {
        float best = len_s[0]; int bi = 0;
        for (int oo = 1; oo < 10; ++oo) if (len_s[oo] > best) { best = len_s[oo]; bi = oo; }
        sel_s = bi;
    }
    __syncthreads();
    const int s = sel_s;
    float acc = b1[t];
    const float* wrow = w1 + (size_t)(s * 16) * 512 + t;
#pragma unroll
    for (int j = 0; j < 16; ++j) acc = fmaf(v_s[s * 16 + j], wrow[j * 512], acc);
    h1d[(size_t)b * 512 + t] = fmaxf(acc, 0.f);
}

// ---------- generic small fp32 GEMM + act (M=256 fixed) ----------
template <int ACT>
__global__ __launch_bounds__(256) void mlp_k(const float* __restrict__ A,
                                             const float* __restrict__ Bm,
                                             const float* __restrict__ bias,
                                             float* __restrict__ C, int N, int K) {
    __shared__ float As[64 * 16];
    __shared__ float Bs[16 * 64];
    const int t = threadIdx.x;
    const int tx = t & 15, ty = t >> 4;
    const int m0 = blockIdx.y * 64, n0 = blockIdx.x * 64;
    float acc[4][4] = {};
    const int arow = t >> 2, ac4 = (t & 3) * 4;
    const int brow = t >> 4, bc4 = (t & 15) * 4;
    for (int k0 = 0; k0 < K; k0 += 16) {
        __syncthreads();
        *(float4*)&As[arow * 16 + ac4] = *(const float4*)&A[(size_t)(m0 + arow) * K + k0 + ac4];
        float4 bv = {0.f, 0.f, 0.f, 0.f};
        const int bn = n0 + bc4;
        if (bn + 3 < N) bv = *(const float4*)&Bm[(size_t)(k0 + brow) * N + bn];
        *(float4*)&Bs[brow * 64 + bc4] = bv;
        __syncthreads();
#pragma unroll
        for (int k = 0; k < 16; ++k) {
            float av[4], bvv[4];
#pragma unroll
            for (int r = 0; r < 4; ++r) av[r] = As[(ty * 4 + r) * 16 + k];
#pragma unroll
            for (int c = 0; c < 4; ++c) bvv[c] = Bs[k * 64 + tx * 4 + c];
#pragma unroll
            for (int r = 0; r < 4; ++r)
#pragma unroll
                for (int c = 0; c < 4; ++c) acc[r][c] = fmaf(av[r], bvv[c], acc[r][c]);
        }
    }
#pragma unroll
    for (int r = 0; r < 4; ++r) {
        const int m = m0 + ty * 4 + r;
#pragma unroll
        for (int c = 0; c < 4; ++c) {
            const int n = n0 + tx * 4 + c;
            if (n < N) {
                float v = acc[r][c] + bias[n];
                if (ACT == 0) v = fmaxf(v, 0.f);
                else v = 1.f / (1.f + expf(-v));
                C[(size_t)m * N + n] = v;
            }
        }
    }
}

// ---------- launcher ----------
extern "C" void kernel_launch(void* const* d_in, const int* in_sizes, int n_in,
                              void* d_out, int out_size, void* d_ws, size_t ws_size,
                              hipStream_t stream) {
    const float* x   = (const float*)d_in[0];
    const float* w1  = (const float*)d_in[1];
    const float* b1  = (const float*)d_in[2];
    const float* w2  = (const float*)d_in[3];
    const float* b2  = (const float*)d_in[4];
    const float* Wc  = (const float*)d_in[5];
    const float* dw1 = (const float*)d_in[6];
    const float* db1 = (const float*)d_in[7];
    const float* dw2 = (const float*)d_in[8];
    const float* db2 = (const float*)d_in[9];
    const float* dw3 = (const float*)d_in[10];
    const float* db3 = (const float*)d_in[11];
    float* out = (float*)d_out;

    char* ws = (char*)d_ws;
    // conv staging (dead after squash_u_k):
    unsigned short* H1T  = (unsigned short*)(ws + 0);          // 52,428,800 B
    unsigned short* W2T  = (unsigned short*)(ws + 52428800);   // 10,616,832 B
    unsigned short* PART = (unsigned short*)(ws + 63045632);   // 37,748,736 B (bf16, z=8)
    // Wr2 lives in dead-PART space; consumed by s0_k BEFORE uhat_k clobbers it:
    float*          WR2  = (float*)(ws + 63045632);            //  5,898,240 B
    unsigned short* UHAT = (unsigned short*)(ws + 0);          // 94,371,840 B
    float* U    = (float*)(ws + 100794368);                    //  9,437,184 B (dead after uhat_k)
    float* BL   = (float*)(ws + 94371840);                     // 11,796,480 B (live iter1->iter2; overlaps dead U tail)
    float* S012 = (float*)(ws + 110231552);                    //    491,520 B (after U; no overlap)
    float* H1D  = (float*)(ws + 94371840);                     //    524,288 B (in dead-BL space, after iter2)
    float* H2D  = (float*)(ws + 94896128);                     //  1,048,576 B

    float* S0 = S012, *S1 = S012 + 40960, *S2 = S012 + 81920;

    conv1_k<<<512, 256, 0, stream>>>(x, w1, b1, H1T);
    w2t_k<<<512, 256, 0, stream>>>(w2, W2T);
    conv2_k<<<1152, 256, 0, stream>>>(H1T, W2T, PART);
    squash_u_k<<<512, 256, 0, stream>>>(PART, b2, U);
    wr_k<<<160, 256, 0, stream>>>(Wc, WR2);
    hipMemsetAsync(S012, 0, 3 * 40960 * sizeof(float), stream);
    s0_k<<<dim3(256, 4), 160, 0, stream>>>(U, WR2, S0);
    uhat_k<<<1152, 256, 0, stream>>>(Wc, U, UHAT);
    route_iter_k<1><<<dim3(256, 9), 256, 0, stream>>>(UHAT, S0, BL, S1);
    route_iter_k<2><<<dim3(256, 9), 256, 0, stream>>>(UHAT, S1, BL, S2);
    final_k<<<256, 512, 0, stream>>>(S2, dw1, db1, out, H1D);
    mlp_k<0><<<dim3(16, 4), 256, 0, stream>>>(H1D, dw2, db2, H2D, 1024, 512);
    mlp_k<1><<<dim3(13, 4), 256, 0, stream>>>(H2D, dw3, db3, out + 2560, 784, 1024);
}

// Round 7
// 552.545 us; speedup vs baseline: 1.2967x; 1.2967x over previous
//
#include <hip/hip_runtime.h>
#include <cstdint>
#include <cstddef>

// ---------- types / helpers ----------
typedef __bf16 bf16x8 __attribute__((ext_vector_type(8)));
typedef float  floatx4 __attribute__((ext_vector_type(4)));
typedef unsigned short ushort8 __attribute__((ext_vector_type(8)));
typedef unsigned short ushort4v __attribute__((ext_vector_type(4)));

__device__ __forceinline__ float bf2f(unsigned short u) {
    union { unsigned int u32; float f; } x; x.u32 = ((unsigned int)u) << 16; return x.f;
}
__device__ __forceinline__ float bflo(unsigned int u) {
    union { unsigned int u32; float f; } x; x.u32 = u << 16; return x.f;
}
__device__ __forceinline__ float bfhi(unsigned int u) {
    union { unsigned int u32; float f; } x; x.u32 = u & 0xffff0000u; return x.f;
}
__device__ __forceinline__ unsigned short f2bf(float f) {
    union { float f; unsigned int u; } x; x.f = f;
    unsigned int u = x.u;
    unsigned int r = (u + 0x7fffu + ((u >> 16) & 1u)) >> 16;   // RNE
    return (unsigned short)r;
}

#define GLOBAL_U32 const __attribute__((address_space(1))) unsigned int*
#define LDS_U32 __attribute__((address_space(3))) unsigned int*
__device__ __forceinline__ void async_cp16(const void* g, void* l) {
    __builtin_amdgcn_global_load_lds((GLOBAL_U32)g, (LDS_U32)l, 16, 0, 0);
}

// ---------- conv1 (oh-split x2): x[256,1,28,28]*w[256,1,9,9] -> h1t bf16 [b][20][20][256] ----------
__global__ __launch_bounds__(256) void conv1_k(const float* __restrict__ x,
                                               const float* __restrict__ w,
                                               const float* __restrict__ bias,
                                               unsigned short* __restrict__ h1t) {
    const int bb = blockIdx.x, t = threadIdx.x;
    const int b = bb >> 1, h = bb & 1;
    const int oh0 = h * 10;
    __shared__ float xs[18 * 28];
    for (int idx = t; idx < 504; idx += 256) xs[idx] = x[b * 784 + oh0 * 28 + idx];
    __syncthreads();
    const float* wr = w + t * 81;   // thread t = output channel t
    const float bv = bias[t];
    for (int ohl = 0; ohl < 10; ++ohl) {
        float acc[20];
#pragma unroll
        for (int ow = 0; ow < 20; ++ow) acc[ow] = bv;
#pragma unroll
        for (int kh = 0; kh < 9; ++kh) {
            float xr[28];
            const float* xrow = &xs[(ohl + kh) * 28];
#pragma unroll
            for (int q = 0; q < 7; ++q) *(float4*)&xr[q * 4] = *(const float4*)&xrow[q * 4];
#pragma unroll
            for (int kw = 0; kw < 9; ++kw) {
                const float wv = wr[kh * 9 + kw];
#pragma unroll
                for (int ow = 0; ow < 20; ++ow) acc[ow] = fmaf(xr[ow + kw], wv, acc[ow]);
            }
        }
        unsigned short* orow = h1t + (size_t)((b * 20 + oh0 + ohl) * 20) * 256 + t;
#pragma unroll
        for (int ow = 0; ow < 20; ++ow) orow[ow * 256] = f2bf(acc[ow]);
    }
}

// ---------- w2 transform: OIHW fp32 [oc][ic][81] -> bf16 [oc][tap*256+ic] ----------
__global__ __launch_bounds__(256) void w2t_k(const float* __restrict__ w2,
                                             unsigned short* __restrict__ w2t) {
    const int oc = blockIdx.x >> 1, half = blockIdx.x & 1, t = threadIdx.x;
    __shared__ float ws[10368];                       // 128 ic * 81 taps
    const float* src = w2 + (size_t)oc * 20736 + half * 128 * 81;
    for (int idx = t; idx < 10368; idx += 256) ws[idx] = src[idx];
    __syncthreads();
    unsigned short* dst = w2t + (size_t)oc * 20736 + half * 128;
    for (int idx = t; idx < 10368; idx += 256) {
        const int tap = idx >> 7, icl = idx & 127;
        dst[tap * 256 + icl] = f2bf(ws[icl * 81 + tap]);
    }
}

// ---------- conv2 as implicit GEMM, bf16 MFMA, split-K x8, BK=64, swizzled LDS ----------
__device__ __forceinline__ int c2_rowbase(int m) {
    const int b = m / 36, sp = m % 36;
    const int oh = sp / 6, ow = sp % 6;
    return (b * 400 + oh * 40 + ow * 2) * 256;        // element offset into h1t
}

__global__ __launch_bounds__(256) void conv2_k(const unsigned short* __restrict__ h1t,
                                               const unsigned short* __restrict__ w2t,
                                               unsigned short* __restrict__ part) {
    const int t = threadIdx.x;
    // XCD-locality swizzle: bx-siblings of one (by,z) are 8 ids apart (same
    // XCD under round-robin), z decorrelated from XCD. Pure-perf bijection.
    const int id = blockIdx.x;                        // 0..1151
    const int bx = (id >> 3) & 1;
    const int by = id >> 4;                           // 0..71
    const int z  = ((id & 7) + by) & 7;               // 0..7
    __shared__ unsigned short At[128 * 64];           // m rows, 64 bf16 (K-pair)
    __shared__ unsigned short Bt[128 * 64];           // oc rows

    const int oc0 = bx * 128;

    // staging: each thread stages 4 A-units and 4 B-units (16B each).
    // LDS slot a = t + 256*k; row = a>>3, phys slot s = a&7 holds logical
    // unit u = s ^ (row&7)  (bank-conflict-free b128 reads).
    int aRB[4], aCU[4], bBase[4];
#pragma unroll
    for (int k = 0; k < 4; ++k) {
        const int a = t + 256 * k;
        const int r = a >> 3, s = a & 7;
        const int u = s ^ (r & 7);
        aRB[k] = c2_rowbase(by * 128 + r) + (u & 3) * 8;
        aCU[k] = u >> 2;                              // which chunk of the pair
        bBase[k] = (oc0 + r) * 20736 + (u >> 2) * 32 + (u & 3) * 8;
    }

    const int lane = t & 63, l15 = lane & 15, quad = lane >> 4;
    const int wave = t >> 6;
    const int wOC = (wave & 1) * 64, wM = (wave >> 1) * 64;

    // fragment LDS offsets (ushort units): row stride 64, unit u = h*4+quad
    int aO[2][4], bO[2][4];
#pragma unroll
    for (int i = 0; i < 4; ++i) {
        const int R = wOC + i * 16 + l15;             // oc row (A-operand from Bt)
#pragma unroll
        for (int h = 0; h < 2; ++h)
            aO[h][i] = R * 64 + (((h * 4 + quad) ^ (R & 7)) << 3);
    }
#pragma unroll
    for (int j = 0; j < 4; ++j) {
        const int R = wM + j * 16 + l15;              // m row (B-operand from At)
#pragma unroll
        for (int h = 0; h < 2; ++h)
            bO[h][j] = R * 64 + (((h * 4 + quad) ^ (R & 7)) << 3);
    }

    floatx4 acc[4][4];
#pragma unroll
    for (int i = 0; i < 4; ++i)
#pragma unroll
        for (int j = 0; j < 4; ++j) acc[i][j] = (floatx4){0.f, 0.f, 0.f, 0.f};

    // K = 648 chunks = 324 pairs; z covers pairs [p0,p1)
    const int p0 = (324 * z) >> 3, p1 = (324 * (z + 1)) >> 3;
    for (int p = p0; p < p1; ++p) {
        const int tap = p >> 2;                       // both chunks of a pair share tap
        const int kh = tap / 9, kw = tap - 9 * kh;
        const int aoffB = (kh * 20 + kw) * 256;
        const int ce7 = (2 * p) & 7;
        __syncthreads();
#pragma unroll
        for (int k = 0; k < 4; ++k)
            async_cp16(h1t + aRB[k] + aoffB + (ce7 + aCU[k]) * 32, At + (t + 256 * k) * 8);
#pragma unroll
        for (int k = 0; k < 4; ++k)
            async_cp16(w2t + bBase[k] + p * 64, Bt + (t + 256 * k) * 8);
        __syncthreads();
#pragma unroll
        for (int h = 0; h < 2; ++h) {
            bf16x8 aF[4], bF[4];
#pragma unroll
            for (int i = 0; i < 4; ++i) aF[i] = *(const bf16x8*)(Bt + aO[h][i]);
#pragma unroll
            for (int j = 0; j < 4; ++j) bF[j] = *(const bf16x8*)(At + bO[h][j]);
#pragma unroll
            for (int i = 0; i < 4; ++i)
#pragma unroll
                for (int j = 0; j < 4; ++j)
                    acc[i][j] = __builtin_amdgcn_mfma_f32_16x16x32_bf16(aF[i], bF[j], acc[i][j], 0, 0, 0);
        }
    }

    // epilogue: D[reg->oc][lane->m]; pack 4 bf16 along n, store to PART[z][m][n]
    unsigned short* pz = part + (size_t)z * 2359296;
#pragma unroll
    for (int i = 0; i < 4; ++i) {
        const int n0 = oc0 + wOC + i * 16 + quad * 4;
#pragma unroll
        for (int j = 0; j < 4; ++j) {
            const int m = by * 128 + wM + j * 16 + l15;
            ushort4v pk;
#pragma unroll
            for (int r = 0; r < 4; ++r) pk[r] = f2bf(acc[i][j][r]);
            *(ushort4v*)(pz + (size_t)m * 256 + n0) = pk;
        }
    }
}

// ---------- reduce split-K(bf16 x8) + bias + squash(axis=w) -> u[b][1152][8] (half-split x2) ----------
__global__ __launch_bounds__(256) void squash_u_k(const unsigned short* __restrict__ part,
                                                  const float* __restrict__ bias,
                                                  float* __restrict__ u) {
    const int bb = blockIdx.x, t = threadIdx.x;
    const int b = bb >> 1, h = bb & 1;
    __shared__ float hs[4608];
    const size_t base = (size_t)b * 9216 + h * 4608;
    for (int q = t; q < 2304; q += 256) {
        const int idx = q * 2;
        float v0 = bias[idx & 255], v1 = bias[(idx + 1) & 255];
#pragma unroll
        for (int z = 0; z < 8; ++z) {
            const unsigned int uu = *(const unsigned int*)(part + (size_t)z * 2359296 + base + idx);
            v0 += bflo(uu);
            v1 += bfhi(uu);
        }
        hs[idx] = v0; hs[idx + 1] = v1;
    }
    __syncthreads();
    for (int gq = t; gq < 768; gq += 256) {           // groups (c, oh-local), squash over ow(6)
        const int c = gq / 3, ohl = gq % 3;
        const int oh = h * 3 + ohl;
        float s[6], sq = 0.f;
#pragma unroll
        for (int ow = 0; ow < 6; ++ow) { s[ow] = hs[(ohl * 6 + ow) * 256 + c]; sq = fmaf(s[ow], s[ow], sq); }
        const float norm = sqrtf(sq);
        const float f = (sq / (1.0f + sq)) / (norm + 1e-7f);
        float* up = u + (size_t)b * 9216 + c * 36 + oh * 6;
#pragma unroll
        for (int ow = 0; ow < 6; ++ow) up[ow] = s[ow] * f;
    }
}

// ---------- u_hat[b][i][o*16+d] bf16 = sum_e W[o,i,d,e]*u[b,i,e] ----------
__global__ __launch_bounds__(256) void uhat_k(const float* __restrict__ Wc,
                                              const float* __restrict__ u,
                                              unsigned short* __restrict__ uhat) {
    const int i = blockIdx.x, t = threadIdx.x;       // t = b
    __shared__ float Wl[1280];                       // [o][d*8+e]
    __shared__ unsigned short Ul[128 * 168];         // padded transpose buffer (43 KB)
    for (int idx = t; idx < 1280; idx += 256) {
        const int o = idx >> 7, r = idx & 127;
        Wl[idx] = Wc[((size_t)o * 1152 + i) * 128 + r];
    }
    float ur[8];
    *(float4*)&ur[0] = *(const float4*)(u + (size_t)t * 9216 + i * 8);
    *(float4*)&ur[4] = *(const float4*)(u + (size_t)t * 9216 + i * 8 + 4);
    __syncthreads();
    unsigned short val[160];
#pragma unroll 1
    for (int o = 0; o < 10; ++o) {
#pragma unroll
        for (int d = 0; d < 16; ++d) {
            const float* wp = &Wl[o * 128 + d * 8];
            float a = 0.f;
#pragma unroll
            for (int e = 0; e < 8; ++e) a = fmaf(wp[e], ur[e], a);
            val[o * 16 + d] = f2bf(a);
        }
    }
#pragma unroll 1
    for (int h = 0; h < 2; ++h) {
        __syncthreads();
        if ((t >> 7) == h) {
            unsigned short* row = &Ul[(t & 127) * 168];
#pragma unroll
            for (int q = 0; q < 20; ++q) *(ushort8*)(row + q * 8) = *(const ushort8*)(val + q * 8);
        }
        __syncthreads();
        for (int idx = t; idx < 2560; idx += 256) {
            const int r = idx / 20, q = idx % 20;
            const int b = h * 128 + r;
            *(ushort8*)(uhat + ((size_t)b * 1152 + i) * 160 + q * 8) =
                *(const ushort8*)(&Ul[r * 168 + q * 8]);
        }
    }
}

// ---------- routing iteration 0: S0[b][160] = 0.1 * sum_i u_hat ----------
__global__ __launch_bounds__(256) void route_iter0_k(const unsigned int* __restrict__ uhat32,
                                                     float* __restrict__ S0) {
    const int b = blockIdx.x, i0 = blockIdx.y * 128, t = threadIdx.x;
    const int th = t & 127, hi = t >> 7;
    if (th >= 80) return;
    const unsigned int* p = uhat32 + ((size_t)b * 1152 + i0 + hi * 64) * 80 + th;
    float ax = 0.f, ay = 0.f;
#pragma unroll 8
    for (int i = 0; i < 64; ++i) {
        const unsigned int uu = p[i * 80];
        ax += bflo(uu);
        ay += bfhi(uu);
    }
    atomicAdd(&S0[b * 160 + 2 * th], 0.1f * ax);
    atomicAdd(&S0[b * 160 + 2 * th + 1], 0.1f * ay);
}

// ---------- fused routing iteration: squash(S_in) + logit update + softmax + weighted sum ----------
template <int ITER>
__global__ __launch_bounds__(256) void route_iter_k(const unsigned short* __restrict__ uhat,
                                                    const float* __restrict__ S_in,
                                                    float* __restrict__ BL,
                                                    float* __restrict__ S_out) {
    const int b = blockIdx.x, i0 = blockIdx.y * 128, t = threadIdx.x;
    __shared__ __align__(16) unsigned short Ul[128 * 160];   // 40960 B
    __shared__ float Vl[160];
    __shared__ float cT[10 * 132];
    __shared__ float dots[128 * 10];

    const char* gsrc = (const char*)(uhat + ((size_t)b * 1152 + i0) * 160);
#pragma unroll
    for (int rep = 0; rep < 10; ++rep)
        async_cp16(gsrc + rep * 4096 + t * 16, (char*)Ul + rep * 4096 + t * 16);

    // phase 0: squash S_in -> Vl (redundant per block; 160 floats)
    if (t < 160) {
        const float x = S_in[b * 160 + t];
        float sq = x * x;
        sq += __shfl_xor(sq, 1, 16);
        sq += __shfl_xor(sq, 2, 16);
        sq += __shfl_xor(sq, 4, 16);
        sq += __shfl_xor(sq, 8, 16);
        const float norm = sqrtf(sq);
        const float f = (sq / (1.f + sq)) / (norm + 1e-7f);
        Vl[t] = x * f;
    }
    __syncthreads();                                  // drains async + Vl visible

    // p1a mapping: o = t%10 fixed per thread, strip s = t/10 (250 active)
    const int o = t % 10, s = t / 10;
    float vr[16];
    if (t < 250) {
#pragma unroll
        for (int q = 0; q < 4; ++q)
            *(float4*)&vr[q * 4] = *(const float4*)(&Vl[o * 16 + q * 4]);
    }

    // p1a: dots[i][o] = sum_d u_hat[i,o,d] * v[o,d]
    if (t < 250) {
#pragma unroll
        for (int rep = 0; rep < 6; ++rep) {
            const int i = s + 25 * rep;
            if (i < 128) {
                const ushort8 ua = *(const ushort8*)(Ul + i * 160 + o * 16);
                const ushort8 ub = *(const ushort8*)(Ul + i * 160 + o * 16 + 8);
                float dot = 0.f;
#pragma unroll
                for (int d = 0; d < 8; ++d) dot = fmaf(bf2f(ua[d]), vr[d], dot);
#pragma unroll
                for (int d = 0; d < 8; ++d) dot = fmaf(bf2f(ub[d]), vr[8 + d], dot);
                dots[i * 10 + o] = dot;
            }
        }
    }
    __syncthreads();

    // p1b: per-i logits + softmax -> cT[o][i]
    if (t < 128) {
        float bl[10];
#pragma unroll
        for (int oo = 0; oo < 10; ++oo) bl[oo] = dots[t * 10 + oo];
        if (ITER == 2) {
#pragma unroll
            for (int oo = 0; oo < 10; ++oo) bl[oo] += BL[(size_t)b * 11520 + oo * 1152 + i0 + t];
        } else {
#pragma unroll
            for (int oo = 0; oo < 10; ++oo) BL[(size_t)b * 11520 + oo * 1152 + i0 + t] = bl[oo];
        }
        float mx = bl[0];
#pragma unroll
        for (int oo = 1; oo < 10; ++oo) mx = fmaxf(mx, bl[oo]);
        float ex[10], sum = 0.f;
#pragma unroll
        for (int oo = 0; oo < 10; ++oo) { ex[oo] = expf(bl[oo] - mx); sum += ex[oo]; }
        const float inv = 1.f / sum;
#pragma unroll
        for (int oo = 0; oo < 10; ++oo) cT[oo * 132 + t] = ex[oo] * inv;
    }
    __syncthreads();

    // p2: S_out[b][160] += sum_i c[i][o] * u_hat[i][od]  (two 64-i halves)
    const int th = t & 127, hi = t >> 7;
    if (th < 80) {
        const int o8 = th >> 3;
        const unsigned int* base = (const unsigned int*)Ul + (size_t)hi * 64 * 80 + th;
        const float* cb = &cT[o8 * 132 + hi * 64];
        float ax = 0.f, ay = 0.f;
#pragma unroll 4
        for (int ii = 0; ii < 64; ++ii) {
            const float c = cb[ii];
            const unsigned int uu = base[ii * 80];
            ax = fmaf(c, bflo(uu), ax);
            ay = fmaf(c, bfhi(uu), ay);
        }
        atomicAdd(&S_out[b * 160 + 2 * th], ax);
        atomicAdd(&S_out[b * 160 + 2 * th + 1], ay);
    }
}

// ---------- final: squash S2 -> lengths, argmax + fused decoder layer 1 ----------
__global__ __launch_bounds__(512) void final_k(const float* __restrict__ S,
                                               const float* __restrict__ w1,
                                               const float* __restrict__ b1,
                                               float* __restrict__ out_len,
                                               float* __restrict__ h1d) {
    const int b = blockIdx.x, t = threadIdx.x;
    __shared__ float v_s[160];
    __shared__ float len_s[10];
    __shared__ int sel_s;
    if (t < 160) {
        const float x = S[b * 160 + t];
        float sq = x * x;
        sq += __shfl_xor(sq, 1, 16);
        sq += __shfl_xor(sq, 2, 16);
        sq += __shfl_xor(sq, 4, 16);
        sq += __shfl_xor(sq, 8, 16);
        const float norm = sqrtf(sq);
        const float f = (sq / (1.f + sq)) / (norm + 1e-7f);
        v_s[t] = x * f;
        if ((t & 15) == 0) {
            const float len = f * norm;
            len_s[t >> 4] = len;
            out_len[b * 10 + (t >> 4)] = len;
        }
    }
    __syncthreads();
    if (t == 0) {
        float best = len_s[0]; int bi = 0;
        for (int oo = 1; oo < 10; ++oo) if (len_s[oo] > best) { best = len_s[oo]; bi = oo; }
        sel_s = bi;
    }
    __syncthreads();
    const int s = sel_s;
    float acc = b1[t];
    const float* wrow = w1 + (size_t)(s * 16) * 512 + t;
#pragma unroll
    for (int j = 0; j < 16; ++j) acc = fmaf(v_s[s * 16 + j], wrow[j * 512], acc);
    h1d[(size_t)b * 512 + t] = fmaxf(acc, 0.f);
}

// ---------- generic small fp32 GEMM + act (M=256 fixed) ----------
template <int ACT>
__global__ __launch_bounds__(256) void mlp_k(const float* __restrict__ A,
                                             const float* __restrict__ Bm,
                                             const float* __restrict__ bias,
                                             float* __restrict__ C, int N, int K) {
    __shared__ float As[64 * 16];
    __shared__ float Bs[16 * 64];
    const int t = threadIdx.x;
    const int tx = t & 15, ty = t >> 4;
    const int m0 = blockIdx.y * 64, n0 = blockIdx.x * 64;
    float acc[4][4] = {};
    const int arow = t >> 2, ac4 = (t & 3) * 4;
    const int brow = t >> 4, bc4 = (t & 15) * 4;
    for (int k0 = 0; k0 < K; k0 += 16) {
        __syncthreads();
        *(float4*)&As[arow * 16 + ac4] = *(const float4*)&A[(size_t)(m0 + arow) * K + k0 + ac4];
        float4 bv = {0.f, 0.f, 0.f, 0.f};
        const int bn = n0 + bc4;
        if (bn + 3 < N) bv = *(const float4*)&Bm[(size_t)(k0 + brow) * N + bn];
        *(float4*)&Bs[brow * 64 + bc4] = bv;
        __syncthreads();
#pragma unroll
        for (int k = 0; k < 16; ++k) {
            float av[4], bvv[4];
#pragma unroll
            for (int r = 0; r < 4; ++r) av[r] = As[(ty * 4 + r) * 16 + k];
#pragma unroll
            for (int c = 0; c < 4; ++c) bvv[c] = Bs[k * 64 + tx * 4 + c];
#pragma unroll
            for (int r = 0; r < 4; ++r)
#pragma unroll
                for (int c = 0; c < 4; ++c) acc[r][c] = fmaf(av[r], bvv[c], acc[r][c]);
        }
    }
#pragma unroll
    for (int r = 0; r < 4; ++r) {
        const int m = m0 + ty * 4 + r;
#pragma unroll
        for (int c = 0; c < 4; ++c) {
            const int n = n0 + tx * 4 + c;
            if (n < N) {
                float v = acc[r][c] + bias[n];
                if (ACT == 0) v = fmaxf(v, 0.f);
                else v = 1.f / (1.f + expf(-v));
                C[(size_t)m * N + n] = v;
            }
        }
    }
}

// ---------- launcher ----------
extern "C" void kernel_launch(void* const* d_in, const int* in_sizes, int n_in,
                              void* d_out, int out_size, void* d_ws, size_t ws_size,
                              hipStream_t stream) {
    const float* x   = (const float*)d_in[0];
    const float* w1  = (const float*)d_in[1];
    const float* b1  = (const float*)d_in[2];
    const float* w2  = (const float*)d_in[3];
    const float* b2  = (const float*)d_in[4];
    const float* Wc  = (const float*)d_in[5];
    const float* dw1 = (const float*)d_in[6];
    const float* db1 = (const float*)d_in[7];
    const float* dw2 = (const float*)d_in[8];
    const float* db2 = (const float*)d_in[9];
    const float* dw3 = (const float*)d_in[10];
    const float* db3 = (const float*)d_in[11];
    float* out = (float*)d_out;

    char* ws = (char*)d_ws;
    // conv staging (dead after squash_u_k), then reused by UHAT:
    unsigned short* H1T  = (unsigned short*)(ws + 0);          // 52,428,800 B
    unsigned short* W2T  = (unsigned short*)(ws + 52428800);   // 10,616,832 B
    unsigned short* PART = (unsigned short*)(ws + 63045632);   // 37,748,736 B (bf16, z=8)
    unsigned short* UHAT = (unsigned short*)(ws + 0);          // 94,371,840 B (aliases dead staging)
    float* U    = (float*)(ws + 100794368);                    //  9,437,184 B (dead after uhat_k)
    float* BL   = (float*)(ws + 94371840);                     // 11,796,480 B (live iter1->iter2; overlaps dead U tail)
    float* S012 = (float*)(ws + 110231552);                    //    491,520 B (after U; no overlap)
    float* H1D  = (float*)(ws + 94371840);                     //    524,288 B (dead-BL space, after iter2)
    float* H2D  = (float*)(ws + 94896128);                     //  4,194,304 B region

    float* S0 = S012, *S1 = S012 + 40960, *S2 = S012 + 81920;

    conv1_k<<<512, 256, 0, stream>>>(x, w1, b1, H1T);
    w2t_k<<<512, 256, 0, stream>>>(w2, W2T);
    conv2_k<<<1152, 256, 0, stream>>>(H1T, W2T, PART);
    squash_u_k<<<512, 256, 0, stream>>>(PART, b2, U);
    uhat_k<<<1152, 256, 0, stream>>>(Wc, U, UHAT);
    hipMemsetAsync(S012, 0, 3 * 40960 * sizeof(float), stream);
    route_iter0_k<<<dim3(256, 9), 256, 0, stream>>>((const unsigned int*)UHAT, S0);
    route_iter_k<1><<<dim3(256, 9), 256, 0, stream>>>(UHAT, S0, BL, S1);
    route_iter_k<2><<<dim3(256, 9), 256, 0, stream>>>(UHAT, S1, BL, S2);
    final_k<<<256, 512, 0, stream>>>(S2, dw1, db1, out, H1D);
    mlp_k<0><<<dim3(16, 4), 256, 0, stream>>>(H1D, dw2, db2, H2D, 1024, 512);
    mlp_k<1><<<dim3(13, 4), 256, 0, stream>>>(H2D, dw3, db3, out + 2560, 784, 1024);
}

// Round 8
// 549.999 us; speedup vs baseline: 1.3027x; 1.0046x over previous
//
#include <hip/hip_runtime.h>
#include <cstdint>
#include <cstddef>

// ---------- types / helpers ----------
typedef __bf16 bf16x8 __attribute__((ext_vector_type(8)));
typedef float  floatx4 __attribute__((ext_vector_type(4)));
typedef unsigned short ushort8 __attribute__((ext_vector_type(8)));
typedef unsigned short ushort4v __attribute__((ext_vector_type(4)));

__device__ __forceinline__ float bf2f(unsigned short u) {
    union { unsigned int u32; float f; } x; x.u32 = ((unsigned int)u) << 16; return x.f;
}
__device__ __forceinline__ float bflo(unsigned int u) {
    union { unsigned int u32; float f; } x; x.u32 = u << 16; return x.f;
}
__device__ __forceinline__ float bfhi(unsigned int u) {
    union { unsigned int u32; float f; } x; x.u32 = u & 0xffff0000u; return x.f;
}
__device__ __forceinline__ unsigned short f2bf(float f) {
    union { float f; unsigned int u; } x; x.f = f;
    unsigned int u = x.u;
    unsigned int r = (u + 0x7fffu + ((u >> 16) & 1u)) >> 16;   // RNE
    return (unsigned short)r;
}

#define GLOBAL_U32 const __attribute__((address_space(1))) unsigned int*
#define LDS_U32 __attribute__((address_space(3))) unsigned int*
__device__ __forceinline__ void async_cp16(const void* g, void* l) {
    __builtin_amdgcn_global_load_lds((GLOBAL_U32)g, (LDS_U32)l, 16, 0, 0);
}

// ---------- conv1 (oh-split x2): x[256,1,28,28]*w[256,1,9,9] -> h1t bf16 [b][20][20][256] ----------
__global__ __launch_bounds__(256) void conv1_k(const float* __restrict__ x,
                                               const float* __restrict__ w,
                                               const float* __restrict__ bias,
                                               unsigned short* __restrict__ h1t) {
    const int bb = blockIdx.x, t = threadIdx.x;
    const int b = bb >> 1, h = bb & 1;
    const int oh0 = h * 10;
    __shared__ float xs[18 * 28];
    for (int idx = t; idx < 504; idx += 256) xs[idx] = x[b * 784 + oh0 * 28 + idx];
    __syncthreads();
    const float* wr = w + t * 81;   // thread t = output channel t
    const float bv = bias[t];
    for (int ohl = 0; ohl < 10; ++ohl) {
        float acc[20];
#pragma unroll
        for (int ow = 0; ow < 20; ++ow) acc[ow] = bv;
#pragma unroll
        for (int kh = 0; kh < 9; ++kh) {
            float xr[28];
            const float* xrow = &xs[(ohl + kh) * 28];
#pragma unroll
            for (int q = 0; q < 7; ++q) *(float4*)&xr[q * 4] = *(const float4*)&xrow[q * 4];
#pragma unroll
            for (int kw = 0; kw < 9; ++kw) {
                const float wv = wr[kh * 9 + kw];
#pragma unroll
                for (int ow = 0; ow < 20; ++ow) acc[ow] = fmaf(xr[ow + kw], wv, acc[ow]);
            }
        }
        unsigned short* orow = h1t + (size_t)((b * 20 + oh0 + ohl) * 20) * 256 + t;
#pragma unroll
        for (int ow = 0; ow < 20; ++ow) orow[ow * 256] = f2bf(acc[ow]);
    }
}

// ---------- w2 transform: OIHW fp32 [oc][ic][81] -> bf16 [oc][tap*256+ic] ----------
__global__ __launch_bounds__(256) void w2t_k(const float* __restrict__ w2,
                                             unsigned short* __restrict__ w2t) {
    const int oc = blockIdx.x >> 1, half = blockIdx.x & 1, t = threadIdx.x;
    __shared__ float ws[10368];                       // 128 ic * 81 taps
    const float* src = w2 + (size_t)oc * 20736 + half * 128 * 81;
    for (int idx = t; idx < 10368; idx += 256) ws[idx] = src[idx];
    __syncthreads();
    unsigned short* dst = w2t + (size_t)oc * 20736 + half * 128;
    for (int idx = t; idx < 10368; idx += 256) {
        const int tap = idx >> 7, icl = idx & 127;
        dst[tap * 256 + icl] = f2bf(ws[icl * 81 + tap]);
    }
}

// ---------- conv2 as implicit GEMM, bf16 MFMA, split-K x4, BK=64, swizzled LDS ----------
__device__ __forceinline__ int c2_rowbase(int m) {
    const int b = m / 36, sp = m % 36;
    const int oh = sp / 6, ow = sp % 6;
    return (b * 400 + oh * 40 + ow * 2) * 256;        // element offset into h1t
}

__global__ __launch_bounds__(256) void conv2_k(const unsigned short* __restrict__ h1t,
                                               const unsigned short* __restrict__ w2t,
                                               unsigned short* __restrict__ part) {
    const int t = threadIdx.x;
    // 576 ids: bx-siblings of one (by,z) are 8 ids apart (same XCD under
    // round-robin); z decorrelated from XCD. Verified bijection.
    const int id = blockIdx.x;                        // 0..575
    const int grp = id >> 4, w16 = id & 15;
    const int bx = (w16 >> 3) & 1;
    const int sub = w16 & 7;
    const int by = grp * 2 + (sub >> 2);              // 0..71
    const int z  = ((sub & 3) + by) & 3;              // 0..3
    __shared__ unsigned short At[128 * 64];           // m rows, 64 bf16 (K-pair)
    __shared__ unsigned short Bt[128 * 64];           // oc rows

    const int oc0 = bx * 128;

    // staging: each thread stages 4 A-units and 4 B-units (16B each).
    // LDS slot a = t + 256*k; row = a>>3, phys slot s = a&7 holds logical
    // unit u = s ^ (row&7)  (bank-conflict-free b128 reads).
    int aRB[4], aCU[4], bBase[4];
#pragma unroll
    for (int k = 0; k < 4; ++k) {
        const int a = t + 256 * k;
        const int r = a >> 3, s = a & 7;
        const int u = s ^ (r & 7);
        aRB[k] = c2_rowbase(by * 128 + r) + (u & 3) * 8;
        aCU[k] = u >> 2;                              // which chunk of the pair
        bBase[k] = (oc0 + r) * 20736 + (u >> 2) * 32 + (u & 3) * 8;
    }

    const int lane = t & 63, l15 = lane & 15, quad = lane >> 4;
    const int wave = t >> 6;
    const int wOC = (wave & 1) * 64, wM = (wave >> 1) * 64;

    // fragment LDS offsets (ushort units): row stride 64, unit u = h*4+quad
    int aO[2][4], bO[2][4];
#pragma unroll
    for (int i = 0; i < 4; ++i) {
        const int R = wOC + i * 16 + l15;             // oc row (A-operand from Bt)
#pragma unroll
        for (int h = 0; h < 2; ++h)
            aO[h][i] = R * 64 + (((h * 4 + quad) ^ (R & 7)) << 3);
    }
#pragma unroll
    for (int j = 0; j < 4; ++j) {
        const int R = wM + j * 16 + l15;              // m row (B-operand from At)
#pragma unroll
        for (int h = 0; h < 2; ++h)
            bO[h][j] = R * 64 + (((h * 4 + quad) ^ (R & 7)) << 3);
    }

    floatx4 acc[4][4];
#pragma unroll
    for (int i = 0; i < 4; ++i)
#pragma unroll
        for (int j = 0; j < 4; ++j) acc[i][j] = (floatx4){0.f, 0.f, 0.f, 0.f};

    // K = 648 chunks = 324 pairs; split 4 ways: 81 pairs per z
    const int p0 = 81 * z, p1 = p0 + 81;
    for (int p = p0; p < p1; ++p) {
        const int tap = p >> 2;                       // both chunks of a pair share tap
        const int kh = tap / 9, kw = tap - 9 * kh;
        const int aoffB = (kh * 20 + kw) * 256;
        const int ce7 = (2 * p) & 7;
        __syncthreads();
#pragma unroll
        for (int k = 0; k < 4; ++k)
            async_cp16(h1t + aRB[k] + aoffB + (ce7 + aCU[k]) * 32, At + (t + 256 * k) * 8);
#pragma unroll
        for (int k = 0; k < 4; ++k)
            async_cp16(w2t + bBase[k] + p * 64, Bt + (t + 256 * k) * 8);
        __syncthreads();
#pragma unroll
        for (int h = 0; h < 2; ++h) {
            bf16x8 aF[4], bF[4];
#pragma unroll
            for (int i = 0; i < 4; ++i) aF[i] = *(const bf16x8*)(Bt + aO[h][i]);
#pragma unroll
            for (int j = 0; j < 4; ++j) bF[j] = *(const bf16x8*)(At + bO[h][j]);
#pragma unroll
            for (int i = 0; i < 4; ++i)
#pragma unroll
                for (int j = 0; j < 4; ++j)
                    acc[i][j] = __builtin_amdgcn_mfma_f32_16x16x32_bf16(aF[i], bF[j], acc[i][j], 0, 0, 0);
        }
    }

    // epilogue: D[reg->oc][lane->m]; pack 4 bf16 along n, store to PART[z][m][n]
    unsigned short* pz = part + (size_t)z * 2359296;
#pragma unroll
    for (int i = 0; i < 4; ++i) {
        const int n0 = oc0 + wOC + i * 16 + quad * 4;
#pragma unroll
        for (int j = 0; j < 4; ++j) {
            const int m = by * 128 + wM + j * 16 + l15;
            ushort4v pk;
#pragma unroll
            for (int r = 0; r < 4; ++r) pk[r] = f2bf(acc[i][j][r]);
            *(ushort4v*)(pz + (size_t)m * 256 + n0) = pk;
        }
    }
}

// ---------- reduce split-K(bf16 x4) + bias + squash(axis=w) -> u[b][1152][8] (half-split x2) ----------
__global__ __launch_bounds__(256) void squash_u_k(const unsigned short* __restrict__ part,
                                                  const float* __restrict__ bias,
                                                  float* __restrict__ u) {
    const int bb = blockIdx.x, t = threadIdx.x;
    const int b = bb >> 1, h = bb & 1;
    __shared__ float hs[4608];
    const size_t base = (size_t)b * 9216 + h * 4608;
    for (int q = t; q < 2304; q += 256) {
        const int idx = q * 2;
        float v0 = bias[idx & 255], v1 = bias[(idx + 1) & 255];
#pragma unroll
        for (int z = 0; z < 4; ++z) {
            const unsigned int uu = *(const unsigned int*)(part + (size_t)z * 2359296 + base + idx);
            v0 += bflo(uu);
            v1 += bfhi(uu);
        }
        hs[idx] = v0; hs[idx + 1] = v1;
    }
    __syncthreads();
    for (int gq = t; gq < 768; gq += 256) {           // groups (c, oh-local), squash over ow(6)
        const int c = gq / 3, ohl = gq % 3;
        const int oh = h * 3 + ohl;
        float s[6], sq = 0.f;
#pragma unroll
        for (int ow = 0; ow < 6; ++ow) { s[ow] = hs[(ohl * 6 + ow) * 256 + c]; sq = fmaf(s[ow], s[ow], sq); }
        const float norm = sqrtf(sq);
        const float f = (sq / (1.0f + sq)) / (norm + 1e-7f);
        float* up = u + (size_t)b * 9216 + c * 36 + oh * 6;
#pragma unroll
        for (int ow = 0; ow < 6; ++ow) up[ow] = s[ow] * f;
    }
}

// ---------- u_hat[b][i][o*16+d] bf16 = sum_e W[o,i,d,e]*u[b,i,e] ----------
__global__ __launch_bounds__(256) void uhat_k(const float* __restrict__ Wc,
                                              const float* __restrict__ u,
                                              unsigned short* __restrict__ uhat) {
    const int i = blockIdx.x, t = threadIdx.x;       // t = b
    __shared__ float Wl[1280];                       // [o][d*8+e]
    __shared__ unsigned short Ul[128 * 168];         // padded transpose buffer (43 KB)
    for (int idx = t; idx < 1280; idx += 256) {
        const int o = idx >> 7, r = idx & 127;
        Wl[idx] = Wc[((size_t)o * 1152 + i) * 128 + r];
    }
    float ur[8];
    *(float4*)&ur[0] = *(const float4*)(u + (size_t)t * 9216 + i * 8);
    *(float4*)&ur[4] = *(const float4*)(u + (size_t)t * 9216 + i * 8 + 4);
    __syncthreads();
    unsigned short val[160];
#pragma unroll 1
    for (int o = 0; o < 10; ++o) {
#pragma unroll
        for (int d = 0; d < 16; ++d) {
            const float* wp = &Wl[o * 128 + d * 8];
            float a = 0.f;
#pragma unroll
            for (int e = 0; e < 8; ++e) a = fmaf(wp[e], ur[e], a);
            val[o * 16 + d] = f2bf(a);
        }
    }
#pragma unroll 1
    for (int h = 0; h < 2; ++h) {
        __syncthreads();
        if ((t >> 7) == h) {
            unsigned short* row = &Ul[(t & 127) * 168];
#pragma unroll
            for (int q = 0; q < 20; ++q) *(ushort8*)(row + q * 8) = *(const ushort8*)(val + q * 8);
        }
        __syncthreads();
        for (int idx = t; idx < 2560; idx += 256) {
            const int r = idx / 20, q = idx % 20;
            const int b = h * 128 + r;
            *(ushort8*)(uhat + ((size_t)b * 1152 + i) * 160 + q * 8) =
                *(const ushort8*)(&Ul[r * 168 + q * 8]);
        }
    }
}

// ---------- routing iteration 0: S0[b][160] = 0.1 * sum_i u_hat ----------
__global__ __launch_bounds__(256) void route_iter0_k(const unsigned int* __restrict__ uhat32,
                                                     float* __restrict__ S0) {
    const int b = blockIdx.x, i0 = blockIdx.y * 128, t = threadIdx.x;
    const int th = t & 127, hi = t >> 7;
    if (th >= 80) return;
    const unsigned int* p = uhat32 + ((size_t)b * 1152 + i0 + hi * 64) * 80 + th;
    float ax = 0.f, ay = 0.f;
#pragma unroll 8
    for (int i = 0; i < 64; ++i) {
        const unsigned int uu = p[i * 80];
        ax += bflo(uu);
        ay += bfhi(uu);
    }
    atomicAdd(&S0[b * 160 + 2 * th], 0.1f * ax);
    atomicAdd(&S0[b * 160 + 2 * th + 1], 0.1f * ay);
}

// ---------- fused routing iteration: squash(S_in) + logit update + softmax + weighted sum ----------
template <int ITER>
__global__ __launch_bounds__(256) void route_iter_k(const unsigned short* __restrict__ uhat,
                                                    const float* __restrict__ S_in,
                                                    float* __restrict__ BL,
                                                    float* __restrict__ S_out) {
    const int b = blockIdx.x, i0 = blockIdx.y * 128, t = threadIdx.x;
    __shared__ __align__(16) unsigned short Ul[128 * 160];   // 40960 B
    __shared__ float Vl[160];
    __shared__ float cT[10 * 132];
    __shared__ float dots[128 * 10];

    const char* gsrc = (const char*)(uhat + ((size_t)b * 1152 + i0) * 160);
#pragma unroll
    for (int rep = 0; rep < 10; ++rep)
        async_cp16(gsrc + rep * 4096 + t * 16, (char*)Ul + rep * 4096 + t * 16);

    // phase 0: squash S_in -> Vl (redundant per block; 160 floats)
    if (t < 160) {
        const float x = S_in[b * 160 + t];
        float sq = x * x;
        sq += __shfl_xor(sq, 1, 16);
        sq += __shfl_xor(sq, 2, 16);
        sq += __shfl_xor(sq, 4, 16);
        sq += __shfl_xor(sq, 8, 16);
        const float norm = sqrtf(sq);
        const float f = (sq / (1.f + sq)) / (norm + 1e-7f);
        Vl[t] = x * f;
    }
    __syncthreads();                                  // drains async + Vl visible

    // p1a mapping: o = t%10 fixed per thread, strip s = t/10 (250 active)
    const int o = t % 10, s = t / 10;
    float vr[16];
    if (t < 250) {
#pragma unroll
        for (int q = 0; q < 4; ++q)
            *(float4*)&vr[q * 4] = *(const float4*)(&Vl[o * 16 + q * 4]);
    }

    // p1a: dots[i][o] = sum_d u_hat[i,o,d] * v[o,d]
    if (t < 250) {
#pragma unroll
        for (int rep = 0; rep < 6; ++rep) {
            const int i = s + 25 * rep;
            if (i < 128) {
                const ushort8 ua = *(const ushort8*)(Ul + i * 160 + o * 16);
                const ushort8 ub = *(const ushort8*)(Ul + i * 160 + o * 16 + 8);
                float dot = 0.f;
#pragma unroll
                for (int d = 0; d < 8; ++d) dot = fmaf(bf2f(ua[d]), vr[d], dot);
#pragma unroll
                for (int d = 0; d < 8; ++d) dot = fmaf(bf2f(ub[d]), vr[8 + d], dot);
                dots[i * 10 + o] = dot;
            }
        }
    }
    __syncthreads();

    // p1b: per-i logits + softmax -> cT[o][i]
    if (t < 128) {
        float bl[10];
#pragma unroll
        for (int oo = 0; oo < 10; ++oo) bl[oo] = dots[t * 10 + oo];
        if (ITER == 2) {
#pragma unroll
            for (int oo = 0; oo < 10; ++oo) bl[oo] += BL[(size_t)b * 11520 + oo * 1152 + i0 + t];
        } else {
#pragma unroll
            for (int oo = 0; oo < 10; ++oo) BL[(size_t)b * 11520 + oo * 1152 + i0 + t] = bl[oo];
        }
        float mx = bl[0];
#pragma unroll
        for (int oo = 1; oo < 10; ++oo) mx = fmaxf(mx, bl[oo]);
        float ex[10], sum = 0.f;
#pragma unroll
        for (int oo = 0; oo < 10; ++oo) { ex[oo] = expf(bl[oo] - mx); sum += ex[oo]; }
        const float inv = 1.f / sum;
#pragma unroll
        for (int oo = 0; oo < 10; ++oo) cT[oo * 132 + t] = ex[oo] * inv;
    }
    __syncthreads();

    // p2: S_out[b][160] += sum_i c[i][o] * u_hat[i][od]  (two 64-i halves)
    const int th = t & 127, hi = t >> 7;
    if (th < 80) {
        const int o8 = th >> 3;
        const unsigned int* base = (const unsigned int*)Ul + (size_t)hi * 64 * 80 + th;
        const float* cb = &cT[o8 * 132 + hi * 64];
        float ax = 0.f, ay = 0.f;
#pragma unroll 4
        for (int ii = 0; ii < 64; ++ii) {
            const float c = cb[ii];
            const unsigned int uu = base[ii * 80];
            ax = fmaf(c, bflo(uu), ax);
            ay = fmaf(c, bfhi(uu), ay);
        }
        atomicAdd(&S_out[b * 160 + 2 * th], ax);
        atomicAdd(&S_out[b * 160 + 2 * th + 1], ay);
    }
}

// ---------- final: squash S2 -> lengths, argmax + fused decoder layer 1 ----------
__global__ __launch_bounds__(512) void final_k(const float* __restrict__ S,
                                               const float* __restrict__ w1,
                                               const float* __restrict__ b1,
                                               float* __restrict__ out_len,
                                               float* __restrict__ h1d) {
    const int b = blockIdx.x, t = threadIdx.x;
    __shared__ float v_s[160];
    __shared__ float len_s[10];
    __shared__ int sel_s;
    if (t < 160) {
        const float x = S[b * 160 + t];
        float sq = x * x;
        sq += __shfl_xor(sq, 1, 16);
        sq += __shfl_xor(sq, 2, 16);
        sq += __shfl_xor(sq, 4, 16);
        sq += __shfl_xor(sq, 8, 16);
        const float norm = sqrtf(sq);
        const float f = (sq / (1.f + sq)) / (norm + 1e-7f);
        v_s[t] = x * f;
        if ((t & 15) == 0) {
            const float len = f * norm;
            len_s[t >> 4] = len;
            out_len[b * 10 + (t >> 4)] = len;
        }
    }
    __syncthreads();
    if (t == 0) {
        float best = len_s[0]; int bi = 0;
        for (int oo = 1; oo < 10; ++oo) if (len_s[oo] > best) { best = len_s[oo]; bi = oo; }
        sel_s = bi;
    }
    __syncthreads();
    const int s = sel_s;
    float acc = b1[t];
    const float* wrow = w1 + (size_t)(s * 16) * 512 + t;
#pragma unroll
    for (int j = 0; j < 16; ++j) acc = fmaf(v_s[s * 16 + j], wrow[j * 512], acc);
    h1d[(size_t)b * 512 + t] = fmaxf(acc, 0.f);
}

// ---------- generic small fp32 GEMM + act (M=256 fixed) ----------
template <int ACT>
__global__ __launch_bounds__(256) void mlp_k(const float* __restrict__ A,
                                             const float* __restrict__ Bm,
                                             const float* __restrict__ bias,
                                             float* __restrict__ C, int N, int K) {
    __shared__ float As[64 * 16];
    __shared__ float Bs[16 * 64];
    const int t = threadIdx.x;
    const int tx = t & 15, ty = t >> 4;
    const int m0 = blockIdx.y * 64, n0 = blockIdx.x * 64;
    float acc[4][4] = {};
    const int arow = t >> 2, ac4 = (t & 3) * 4;
    const int brow = t >> 4, bc4 = (t & 15) * 4;
    for (int k0 = 0; k0 < K; k0 += 16) {
        __syncthreads();
        *(float4*)&As[arow * 16 + ac4] = *(const float4*)&A[(size_t)(m0 + arow) * K + k0 + ac4];
        float4 bv = {0.f, 0.f, 0.f, 0.f};
        const int bn = n0 + bc4;
        if (bn + 3 < N) bv = *(const float4*)&Bm[(size_t)(k0 + brow) * N + bn];
        *(float4*)&Bs[brow * 64 + bc4] = bv;
        __syncthreads();
#pragma unroll
        for (int k = 0; k < 16; ++k) {
            float av[4], bvv[4];
#pragma unroll
            for (int r = 0; r < 4; ++r) av[r] = As[(ty * 4 + r) * 16 + k];
#pragma unroll
            for (int c = 0; c < 4; ++c) bvv[c] = Bs[k * 64 + tx * 4 + c];
#pragma unroll
            for (int r = 0; r < 4; ++r)
#pragma unroll
                for (int c = 0; c < 4; ++c) acc[r][c] = fmaf(av[r], bvv[c], acc[r][c]);
        }
    }
#pragma unroll
    for (int r = 0; r < 4; ++r) {
        const int m = m0 + ty * 4 + r;
#pragma unroll
        for (int c = 0; c < 4; ++c) {
            const int n = n0 + tx * 4 + c;
            if (n < N) {
                float v = acc[r][c] + bias[n];
                if (ACT == 0) v = fmaxf(v, 0.f);
                else v = 1.f / (1.f + expf(-v));
                C[(size_t)m * N + n] = v;
            }
        }
    }
}

// ---------- launcher ----------
extern "C" void kernel_launch(void* const* d_in, const int* in_sizes, int n_in,
                              void* d_out, int out_size, void* d_ws, size_t ws_size,
                              hipStream_t stream) {
    const float* x   = (const float*)d_in[0];
    const float* w1  = (const float*)d_in[1];
    const float* b1  = (const float*)d_in[2];
    const float* w2  = (const float*)d_in[3];
    const float* b2  = (const float*)d_in[4];
    const float* Wc  = (const float*)d_in[5];
    const float* dw1 = (const float*)d_in[6];
    const float* db1 = (const float*)d_in[7];
    const float* dw2 = (const float*)d_in[8];
    const float* db2 = (const float*)d_in[9];
    const float* dw3 = (const float*)d_in[10];
    const float* db3 = (const float*)d_in[11];
    float* out = (float*)d_out;

    char* ws = (char*)d_ws;
    // conv staging (dead after squash_u_k), then reused by UHAT:
    unsigned short* H1T  = (unsigned short*)(ws + 0);          // 52,428,800 B
    unsigned short* W2T  = (unsigned short*)(ws + 52428800);   // 10,616,832 B
    unsigned short* PART = (unsigned short*)(ws + 63045632);   // 18,874,368 B (bf16, z=4)
    unsigned short* UHAT = (unsigned short*)(ws + 0);          // 94,371,840 B (aliases dead staging)
    float* U    = (float*)(ws + 100794368);                    //  9,437,184 B (dead after uhat_k)
    float* BL   = (float*)(ws + 94371840);                     // 11,796,480 B (live iter1->iter2; overlaps dead U tail)
    float* S012 = (float*)(ws + 110231552);                    //    491,520 B (after U; no overlap)
    float* H1D  = (float*)(ws + 94371840);                     //    524,288 B (dead-BL space, after iter2)
    float* H2D  = (float*)(ws + 94896128);                     //  4,194,304 B region

    float* S0 = S012, *S1 = S012 + 40960, *S2 = S012 + 81920;

    conv1_k<<<512, 256, 0, stream>>>(x, w1, b1, H1T);
    w2t_k<<<512, 256, 0, stream>>>(w2, W2T);
    conv2_k<<<576, 256, 0, stream>>>(H1T, W2T, PART);
    squash_u_k<<<512, 256, 0, stream>>>(PART, b2, U);
    uhat_k<<<1152, 256, 0, stream>>>(Wc, U, UHAT);
    hipMemsetAsync(S012, 0, 3 * 40960 * sizeof(float), stream);
    route_iter0_k<<<dim3(256, 9), 256, 0, stream>>>((const unsigned int*)UHAT, S0);
    route_iter_k<1><<<dim3(256, 9), 256, 0, stream>>>(UHAT, S0, BL, S1);
    route_iter_k<2><<<dim3(256, 9), 256, 0, stream>>>(UHAT, S1, BL, S2);
    final_k<<<256, 512, 0, stream>>>(S2, dw1, db1, out, H1D);
    mlp_k<0><<<dim3(16, 4), 256, 0, stream>>>(H1D, dw2, db2, H2D, 1024, 512);
    mlp_k<1><<<dim3(13, 4), 256, 0, stream>>>(H2D, dw3, db3, out + 2560, 784, 1024);
}